// Round 1
// baseline (446.725 us; speedup 1.0000x reference)
//
#include <hip/hip_runtime.h>
#include <math.h>

#define NB   64
#define SEQ  1024
#define DIN  32
#define HID  256
#define QT   64
#define KT   64
#define NKT  (SEQ / KT)
#define PADI 36
#define PADS 68

// Precompute A = Wq * Wk^T (32x32) and u = Wk * bq (32) into ws.
__global__ void precompute_kernel(const float* __restrict__ Wq,
                                  const float* __restrict__ Wk,
                                  const float* __restrict__ bq,
                                  float* __restrict__ ws) {
    int t = threadIdx.x;
    for (int e = t; e < DIN * DIN; e += 256) {
        int j = e >> 5, i = e & 31;
        const float* wqr = &Wq[j * HID];
        const float* wkr = &Wk[i * HID];
        float acc = 0.f;
        for (int h = 0; h < HID; h += 4) {
            float4 a = *(const float4*)&wqr[h];
            float4 b = *(const float4*)&wkr[h];
            acc += a.x * b.x + a.y * b.y + a.z * b.z + a.w * b.w;
        }
        ws[e] = acc;
    }
    if (t < DIN) {
        const float* wkr = &Wk[t * HID];
        float acc = 0.f;
        for (int h = 0; h < HID; ++h) acc += wkr[h] * bq[h];
        ws[DIN * DIN + t] = acc;
    }
}

__global__ __launch_bounds__(256) void attn_kernel(
    const float* __restrict__ x,
    const float* __restrict__ ws,
    const float* __restrict__ Wv,
    const float* __restrict__ bv,
    float* __restrict__ out) {

    const int b  = blockIdx.y;
    const int q0 = blockIdx.x * QT;
    const int t  = threadIdx.x;

    __shared__ float A_s[DIN * DIN];
    __shared__ float u_s[DIN];
    __shared__ float G_s[QT * PADI];
    __shared__ float xk_s[KT * PADI];
    __shared__ float Sbuf[QT * PADS];   // xq (prologue) -> P tile (loop) -> O32 (epilogue)
    __shared__ float ck_s[SEQ];
    __shared__ float m_s[QT];
    __shared__ float l_s[QT];
    __shared__ float alpha_s[QT];

    const float* xb = x + (size_t)b * SEQ * DIN;

    // ---------- prologue: load A, u, x_q tile ----------
    for (int e = t; e < DIN * DIN; e += 256) A_s[e] = ws[e];
    if (t < DIN) u_s[t] = ws[DIN * DIN + t];
    {
        int r = t >> 2, c = (t & 3) * 8;
        const float* src = xb + (q0 + r) * DIN + c;
        float4 v0 = *(const float4*)src;
        float4 v1 = *(const float4*)(src + 4);
        *(float4*)&Sbuf[r * PADI + c]     = v0;
        *(float4*)&Sbuf[r * PADI + c + 4] = v1;
    }
    if (t < QT) { m_s[t] = -INFINITY; l_s[t] = 0.f; }
    __syncthreads();

    // ---------- G = xq @ A ----------
    {
        int r = t >> 2, c0 = (t & 3) * 8;
        float acc[8];
        #pragma unroll
        for (int j = 0; j < 8; ++j) acc[j] = 0.f;
        #pragma unroll 8
        for (int j = 0; j < DIN; ++j) {
            float xv = Sbuf[r * PADI + j];
            float4 a0 = *(float4*)&A_s[j * DIN + c0];
            float4 a1 = *(float4*)&A_s[j * DIN + c0 + 4];
            acc[0] = fmaf(xv, a0.x, acc[0]);
            acc[1] = fmaf(xv, a0.y, acc[1]);
            acc[2] = fmaf(xv, a0.z, acc[2]);
            acc[3] = fmaf(xv, a0.w, acc[3]);
            acc[4] = fmaf(xv, a1.x, acc[4]);
            acc[5] = fmaf(xv, a1.y, acc[5]);
            acc[6] = fmaf(xv, a1.z, acc[6]);
            acc[7] = fmaf(xv, a1.w, acc[7]);
        }
        float4 g0 = {acc[0], acc[1], acc[2], acc[3]};
        float4 g1 = {acc[4], acc[5], acc[6], acc[7]};
        *(float4*)&G_s[r * PADI + c0]     = g0;
        *(float4*)&G_s[r * PADI + c0 + 4] = g1;
    }
    // ---------- ck[k] = x_k . u  for all 1024 keys ----------
    for (int k = t; k < SEQ; k += 256) {
        const float* xr = xb + k * DIN;
        float acc = 0.f;
        #pragma unroll
        for (int i = 0; i < DIN; i += 4) {
            float4 v = *(const float4*)&xr[i];
            acc = fmaf(v.x, u_s[i],     acc);
            acc = fmaf(v.y, u_s[i + 1], acc);
            acc = fmaf(v.z, u_s[i + 2], acc);
            acc = fmaf(v.w, u_s[i + 3], acc);
        }
        ck_s[k] = acc;
    }
    __syncthreads();

    float o[8];
    #pragma unroll
    for (int j = 0; j < 8; ++j) o[j] = 0.f;

    const int tq = t >> 4, tk = t & 15;
    const int qg0 = tq * 4, kg0 = tk * 4;
    const int q_own = t >> 2, i0 = (t & 3) * 8;

    for (int kt = 0; kt < NKT; ++kt) {
        // ---- load x_k tile ----
        {
            int r = t >> 2, c = (t & 3) * 8;
            const float* src = xb + (kt * KT + r) * DIN + c;
            float4 v0 = *(const float4*)src;
            float4 v1 = *(const float4*)(src + 4);
            *(float4*)&xk_s[r * PADI + c]     = v0;
            *(float4*)&xk_s[r * PADI + c + 4] = v1;
        }
        __syncthreads();

        // ---- GEMM1: S(4x4 per thread) = G . xk^T  (+ ck) ----
        float sv[4][4];
        #pragma unroll
        for (int qq = 0; qq < 4; ++qq)
            #pragma unroll
            for (int kk = 0; kk < 4; ++kk)
                sv[qq][kk] = ck_s[kt * KT + kg0 + kk];
        #pragma unroll
        for (int i = 0; i < DIN; i += 4) {
            float4 g[4], xv[4];
            #pragma unroll
            for (int qq = 0; qq < 4; ++qq) g[qq] = *(float4*)&G_s[(qg0 + qq) * PADI + i];
            #pragma unroll
            for (int kk = 0; kk < 4; ++kk) xv[kk] = *(float4*)&xk_s[(kg0 + kk) * PADI + i];
            #pragma unroll
            for (int qq = 0; qq < 4; ++qq)
                #pragma unroll
                for (int kk = 0; kk < 4; ++kk) {
                    sv[qq][kk] = fmaf(g[qq].x, xv[kk].x, sv[qq][kk]);
                    sv[qq][kk] = fmaf(g[qq].y, xv[kk].y, sv[qq][kk]);
                    sv[qq][kk] = fmaf(g[qq].z, xv[kk].z, sv[qq][kk]);
                    sv[qq][kk] = fmaf(g[qq].w, xv[kk].w, sv[qq][kk]);
                }
        }

        // ---- online softmax (16 lanes per row group, in-wave) ----
        #pragma unroll
        for (int qq = 0; qq < 4; ++qq) {
            int q = qg0 + qq;
            float rm = fmaxf(fmaxf(sv[qq][0], sv[qq][1]), fmaxf(sv[qq][2], sv[qq][3]));
            rm = fmaxf(rm, __shfl_xor(rm, 1));
            rm = fmaxf(rm, __shfl_xor(rm, 2));
            rm = fmaxf(rm, __shfl_xor(rm, 4));
            rm = fmaxf(rm, __shfl_xor(rm, 8));
            float mo = m_s[q];
            float mn = fmaxf(mo, rm);
            float psum = 0.f;
            #pragma unroll
            for (int kk = 0; kk < 4; ++kk) {
                float p = __expf(sv[qq][kk] - mn);
                sv[qq][kk] = p;
                psum += p;
            }
            psum += __shfl_xor(psum, 1);
            psum += __shfl_xor(psum, 2);
            psum += __shfl_xor(psum, 4);
            psum += __shfl_xor(psum, 8);
            if (tk == 0) {
                float al = __expf(mo - mn);
                m_s[q] = mn;
                l_s[q] = l_s[q] * al + psum;
                alpha_s[q] = al;
            }
            #pragma unroll
            for (int kk = 0; kk < 4; ++kk)
                Sbuf[q * PADS + kg0 + kk] = sv[qq][kk];
        }
        __syncthreads();

        // ---- GEMM2: O += P . xk ----
        float al = alpha_s[q_own];
        #pragma unroll
        for (int j = 0; j < 8; ++j) o[j] *= al;
        #pragma unroll 8
        for (int k = 0; k < KT; ++k) {
            float p = Sbuf[q_own * PADS + k];
            float4 xa = *(float4*)&xk_s[k * PADI + i0];
            float4 xb4 = *(float4*)&xk_s[k * PADI + i0 + 4];
            o[0] = fmaf(p, xa.x,  o[0]);
            o[1] = fmaf(p, xa.y,  o[1]);
            o[2] = fmaf(p, xa.z,  o[2]);
            o[3] = fmaf(p, xa.w,  o[3]);
            o[4] = fmaf(p, xb4.x, o[4]);
            o[5] = fmaf(p, xb4.y, o[5]);
            o[6] = fmaf(p, xb4.z, o[6]);
            o[7] = fmaf(p, xb4.w, o[7]);
        }
        __syncthreads();
    }

    // ---------- finalize: O32 = O / (16 * l), stash in Sbuf ----------
    {
        float inv = 1.0f / (16.0f * l_s[q_own]);
        #pragma unroll
        for (int j = 0; j < 8; ++j) o[j] *= inv;
        float4 w0 = {o[0], o[1], o[2], o[3]};
        float4 w1 = {o[4], o[5], o[6], o[7]};
        *(float4*)&Sbuf[q_own * PADI + i0]     = w0;
        *(float4*)&Sbuf[q_own * PADI + i0 + 4] = w1;
    }
    __syncthreads();

    // ---------- epilogue: Z = O32 @ Wv + bv/16  (h = t) ----------
    {
        float wv[DIN];
        #pragma unroll
        for (int i = 0; i < DIN; ++i) wv[i] = Wv[i * HID + t];
        float bvh = bv[t] * 0.0625f;
        float* outb = out + ((size_t)b * SEQ + q0) * HID + t;
        for (int q = 0; q < QT; ++q) {
            float z = bvh;
            #pragma unroll
            for (int i = 0; i < DIN; i += 4) {
                float4 ov = *(float4*)&Sbuf[q * PADI + i];
                z = fmaf(ov.x, wv[i],     z);
                z = fmaf(ov.y, wv[i + 1], z);
                z = fmaf(ov.z, wv[i + 2], z);
                z = fmaf(ov.w, wv[i + 3], z);
            }
            outb[q * HID] = z;
        }
    }
}

extern "C" void kernel_launch(void* const* d_in, const int* in_sizes, int n_in,
                              void* d_out, int out_size, void* d_ws, size_t ws_size,
                              hipStream_t stream) {
    (void)in_sizes; (void)n_in; (void)out_size; (void)ws_size;
    const float* x  = (const float*)d_in[0];
    const float* Wq = (const float*)d_in[1];
    const float* bq = (const float*)d_in[2];
    const float* Wk = (const float*)d_in[3];
    const float* Wv = (const float*)d_in[5];
    const float* bv = (const float*)d_in[6];
    float* out = (float*)d_out;
    float* ws  = (float*)d_ws;

    precompute_kernel<<<1, 256, 0, stream>>>(Wq, Wk, bq, ws);
    attn_kernel<<<dim3(SEQ / QT, NB), 256, 0, stream>>>(x, ws, Wv, bv, out);
}

// Round 5
// 94.923 us; speedup vs baseline: 4.7062x; 4.7062x over previous
//
#include <hip/hip_runtime.h>
#include <math.h>

#define NB   64
#define SEQ  1024
#define DIN  32
#define HID  256
#define QT   128
#define KT   64
#define NKT  (SEQ/KT)

typedef float        f32x16 __attribute__((ext_vector_type(16)));
typedef short        s16x8  __attribute__((ext_vector_type(8)));
typedef unsigned int u32x4v __attribute__((ext_vector_type(4)));
typedef unsigned int u32x2v __attribute__((ext_vector_type(2)));

#define MFMA32(A,B,C) __builtin_amdgcn_mfma_f32_32x32x16_bf16(A,B,C,0,0,0)

__device__ __forceinline__ unsigned pk_bf16(float lo, float hi) {
  unsigned r;
  asm("v_cvt_pk_bf16_f32 %0, %1, %2" : "=v"(r) : "v"(lo), "v"(hi));
  return r;
}
// two-output permlane32_swap via builtin.
// new_dst = [dst.lo(lanes<32) | src.lo], new_src = [dst.hi | src.hi]
__device__ __forceinline__ void plswap(unsigned &vdst, unsigned &vsrc) {
  u32x2v r = __builtin_amdgcn_permlane32_swap(vdst, vsrc, false, false);
  vdst = r[0]; vsrc = r[1];
}
__device__ __forceinline__ float cross_max(float v) {
  u32x2v r = __builtin_amdgcn_permlane32_swap(__float_as_uint(v), __float_as_uint(v), false, false);
  return fmaxf(__uint_as_float(r[0]), __uint_as_float(r[1]));
}
__device__ __forceinline__ float cross_add(float v) {
  u32x2v r = __builtin_amdgcn_permlane32_swap(__float_as_uint(v), __float_as_uint(v), false, false);
  return __uint_as_float(r[0]) + __uint_as_float(r[1]);
}
__device__ __forceinline__ s16x8 frag4(unsigned a, unsigned b, unsigned c, unsigned d) {
  u32x4v t; t[0]=a; t[1]=b; t[2]=c; t[3]=d;
  return __builtin_bit_cast(s16x8, t);
}
__device__ __forceinline__ unsigned bf16_hi_bits(float f) {  // bf16 RNE bits in low16
  unsigned ux = __float_as_uint(f);
  return (ux + 0x7fffu + ((ux >> 16) & 1u)) >> 16;
}

// ws layout: f32 AT[32][32] (AT[i][j] = sum_h Wq[j,h]Wk[i,h]), f32 u[32],
// then at byte 4224: u32 WvT[256][16] (pk-packed bf16 pairs of Wv^T rows)
__global__ void precompute_kernel(const float* __restrict__ Wq, const float* __restrict__ Wk,
                                  const float* __restrict__ bq, const float* __restrict__ Wv,
                                  float* __restrict__ ws) {
  const int t = threadIdx.x;
  for (int e = t; e < 1024; e += 256) {
    int i = e >> 5, j = e & 31;
    const float* a  = Wq + j * HID;
    const float* b2 = Wk + i * HID;
    float acc = 0.f;
    for (int h = 0; h < HID; h += 4) {
      float4 x1 = *(const float4*)(a + h);
      float4 y1 = *(const float4*)(b2 + h);
      acc = fmaf(x1.x, y1.x, acc); acc = fmaf(x1.y, y1.y, acc);
      acc = fmaf(x1.z, y1.z, acc); acc = fmaf(x1.w, y1.w, acc);
    }
    ws[e] = acc;
  }
  if (t < 32) {
    const float* b2 = Wk + t * HID;
    float acc = 0.f;
    for (int h = 0; h < HID; ++h) acc = fmaf(b2[h], bq[h], acc);
    ws[1024 + t] = acc;
  }
  unsigned* WvTp = (unsigned*)((char*)ws + 4224);
  for (int e = t; e < HID * 16; e += 256) {
    int h = e >> 4, d = e & 15;
    WvTp[e] = pk_bf16(Wv[(2*d) * HID + h], Wv[(2*d+1) * HID + h]);
  }
}

// LDS map (bytes): xk_h[2][64][32]bf16 @0 (2x4096), xk_l @8192, xkT_h[2][32][64]bf16 @16384,
// AT+u f32[1056] @24576. Zbuf (epilogue) aliases @ wid*4224. Total 28800.
__global__ __launch_bounds__(256, 2) void attn_kernel(
    const float* __restrict__ x, const float* __restrict__ ws,
    const float* __restrict__ bv, float* __restrict__ out) {
  __shared__ __align__(16) char smem[28800];
  const int b    = blockIdx.y;
  const int q0   = blockIdx.x * QT;
  const int t    = threadIdx.x;
  const int wid  = t >> 6;
  const int lane = t & 63;
  const int w    = lane >> 5;
  const int lq   = lane & 31;
  const float* xb = x + (size_t)b * SEQ * DIN;

  float* ATs = (float*)(smem + 24576);
  for (int e = t; e < 1056; e += 256) ATs[e] = ws[e];

  // ---- stage tile 0 into buf 0 ----
  {
    const int r = t >> 2, s4 = t & 3;
    const float* src = xb + (size_t)r * DIN + s4 * 8;
    float4 va = *(const float4*)src;
    float4 vb = *(const float4*)(src + 4);
    unsigned h0 = bf16_hi_bits(va.x) | (bf16_hi_bits(va.y) << 16);
    unsigned h1 = bf16_hi_bits(va.z) | (bf16_hi_bits(va.w) << 16);
    unsigned h2 = bf16_hi_bits(vb.x) | (bf16_hi_bits(vb.y) << 16);
    unsigned h3 = bf16_hi_bits(vb.z) | (bf16_hi_bits(vb.w) << 16);
    unsigned l0 = bf16_hi_bits(va.x - __uint_as_float(h0<<16)) | (bf16_hi_bits(va.y - __uint_as_float(h0 & 0xffff0000u)) << 16);
    unsigned l1 = bf16_hi_bits(va.z - __uint_as_float(h1<<16)) | (bf16_hi_bits(va.w - __uint_as_float(h1 & 0xffff0000u)) << 16);
    unsigned l2 = bf16_hi_bits(vb.x - __uint_as_float(h2<<16)) | (bf16_hi_bits(vb.y - __uint_as_float(h2 & 0xffff0000u)) << 16);
    unsigned l3 = bf16_hi_bits(vb.z - __uint_as_float(h3<<16)) | (bf16_hi_bits(vb.w - __uint_as_float(h3 & 0xffff0000u)) << 16);
    int off = r*64 + ((s4 ^ (r & 3)) << 4);
    *(u32x4v*)(smem + off)        = (u32x4v){h0,h1,h2,h3};
    *(u32x4v*)(smem + 8192 + off) = (u32x4v){l0,l1,l2,l3};
    const int ci = t & 31, cr = (t >> 5) * 8;
    const float* cs = xb + (size_t)cr * DIN + ci;
    float c0=cs[0], c1=cs[DIN], c2=cs[2*DIN], c3=cs[3*DIN];
    float c4=cs[4*DIN], c5=cs[5*DIN], c6=cs[6*DIN], c7=cs[7*DIN];
    unsigned t0 = pk_bf16(c0,c1), t1 = pk_bf16(c2,c3), t2 = pk_bf16(c4,c5), t3 = pk_bf16(c6,c7);
    int toff = 16384 + ci*128 + (((t>>5) ^ (ci & 7)) << 4);
    *(u32x4v*)(smem + toff) = (u32x4v){t0,t1,t2,t3};
  }
  __syncthreads();

  // ---- G' = xq*M + u, packed into B-fragments (hi/lo) ----
  float g[16];
  {
    float xq[32];
    const float* xrow = xb + (size_t)(q0 + wid*32 + lq) * DIN;
    #pragma unroll
    for (int c = 0; c < 8; ++c) {
      float4 v = *(const float4*)(xrow + c*4);
      xq[c*4+0]=v.x; xq[c*4+1]=v.y; xq[c*4+2]=v.z; xq[c*4+3]=v.w;
    }
    #pragma unroll
    for (int ii = 0; ii < 16; ++ii) {
      const int i = 8*w + 16*(ii>>3) + (ii&7);
      const float* ar = ATs + i*32;
      float acc = ATs[1024 + i];
      #pragma unroll
      for (int j = 0; j < 8; ++j) {
        float4 av = *(const float4*)(ar + j*4);
        acc = fmaf(xq[j*4+0], av.x, acc);
        acc = fmaf(xq[j*4+1], av.y, acc);
        acc = fmaf(xq[j*4+2], av.z, acc);
        acc = fmaf(xq[j*4+3], av.w, acc);
      }
      g[ii] = acc;
    }
  }
  s16x8 G0h, G0l, G1h, G1l;
  {
    unsigned gh[2][4], gl[2][4];
    #pragma unroll
    for (int Ks = 0; Ks < 2; ++Ks)
      #pragma unroll
      for (int d = 0; d < 4; ++d) {
        float ga = g[Ks*8 + 2*d], gb = g[Ks*8 + 2*d + 1];
        unsigned hp = bf16_hi_bits(ga) | (bf16_hi_bits(gb) << 16);
        unsigned lp = bf16_hi_bits(ga - __uint_as_float(hp<<16)) |
                      (bf16_hi_bits(gb - __uint_as_float(hp & 0xffff0000u)) << 16);
        gh[Ks][d] = hp; gl[Ks][d] = lp;
      }
    G0h = frag4(gh[0][0],gh[0][1],gh[0][2],gh[0][3]);
    G0l = frag4(gl[0][0],gl[0][1],gl[0][2],gl[0][3]);
    G1h = frag4(gh[1][0],gh[1][1],gh[1][2],gh[1][3]);
    G1l = frag4(gl[1][0],gl[1][1],gl[1][2],gl[1][3]);
  }

  f32x16 oacc;
  #pragma unroll
  for (int r = 0; r < 16; ++r) oacc[r] = 0.f;
  float m = -INFINITY, l = 0.f;

  int cur = 0;
  for (int kt = 0; kt < NKT; ++kt) {
    const bool hn = (kt + 1 < NKT);
    float4 va, vb;
    float c0=0,c1=0,c2=0,c3=0,c4=0,c5=0,c6=0,c7=0;
    if (hn) {
      const int r = t >> 2, s4 = t & 3;
      const float* src = xb + (size_t)((kt+1)*KT + r) * DIN + s4*8;
      va = *(const float4*)src;
      vb = *(const float4*)(src + 4);
      const int ci = t & 31, cr = (t >> 5) * 8;
      const float* cs = xb + (size_t)((kt+1)*KT + cr) * DIN + ci;
      c0=cs[0]; c1=cs[DIN]; c2=cs[2*DIN]; c3=cs[3*DIN];
      c4=cs[4*DIN]; c5=cs[5*DIN]; c6=cs[6*DIN]; c7=cs[7*DIN];
    }

    // ---- GEMM1: S^T[64k x 32q] ----
    const char* bh = smem + cur*4096;
    const char* bl = smem + 8192 + cur*4096;
    const int co0 = ((w    ) ^ (lq & 3)) << 4;
    const int co1 = ((w + 2) ^ (lq & 3)) << 4;
    s16x8 ah00 = *(const s16x8*)(bh + lq*64 + co0);
    s16x8 ah01 = *(const s16x8*)(bh + lq*64 + co1);
    s16x8 al00 = *(const s16x8*)(bl + lq*64 + co0);
    s16x8 al01 = *(const s16x8*)(bl + lq*64 + co1);
    s16x8 ah10 = *(const s16x8*)(bh + (32+lq)*64 + co0);
    s16x8 ah11 = *(const s16x8*)(bh + (32+lq)*64 + co1);
    s16x8 al10 = *(const s16x8*)(bl + (32+lq)*64 + co0);
    s16x8 al11 = *(const s16x8*)(bl + (32+lq)*64 + co1);
    f32x16 sa0, sa1;
    #pragma unroll
    for (int r = 0; r < 16; ++r) { sa0[r] = 0.f; sa1[r] = 0.f; }
    sa0 = MFMA32(ah00, G0h, sa0); sa0 = MFMA32(ah00, G0l, sa0); sa0 = MFMA32(al00, G0h, sa0);
    sa0 = MFMA32(ah01, G1h, sa0); sa0 = MFMA32(ah01, G1l, sa0); sa0 = MFMA32(al01, G1h, sa0);
    sa1 = MFMA32(ah10, G0h, sa1); sa1 = MFMA32(ah10, G0l, sa1); sa1 = MFMA32(al10, G0h, sa1);
    sa1 = MFMA32(ah11, G1h, sa1); sa1 = MFMA32(ah11, G1l, sa1); sa1 = MFMA32(al11, G1h, sa1);

    // ---- online softmax (per q = lq; partner lane holds other keys) ----
    float tm = sa0[0];
    #pragma unroll
    for (int r = 1; r < 16; ++r) tm = fmaxf(tm, sa0[r]);
    #pragma unroll
    for (int r = 0; r < 16; ++r) tm = fmaxf(tm, sa1[r]);
    tm = cross_max(tm);
    float mn = fmaxf(m, tm);
    float alpha = __expf(m - mn);
    m = mn;
    float ps = 0.f;
    #pragma unroll
    for (int r = 0; r < 16; ++r) { float p = __expf(sa0[r] - mn); sa0[r] = p; ps += p; }
    #pragma unroll
    for (int r = 0; r < 16; ++r) { float p = __expf(sa1[r] - mn); sa1[r] = p; ps += p; }
    ps = cross_add(ps);
    l = l * alpha + ps;
    #pragma unroll
    for (int r = 0; r < 16; ++r) oacc[r] *= alpha;

    // ---- GEMM2: O^T += xkT * P (P repacked in-register; dst=low-pair!) ----
    const char* bt = smem + 16384 + cur*4096;
    {
      unsigned u0 = pk_bf16(sa0[0], sa0[1]),  u1 = pk_bf16(sa0[2], sa0[3]);
      unsigned v0 = pk_bf16(sa0[4], sa0[5]),  v1 = pk_bf16(sa0[6], sa0[7]);
      plswap(u0, v0); plswap(u1, v1);
      s16x8 at0 = *(const s16x8*)(bt + lq*128 + (((0 + w) ^ (lq & 7)) << 4));
      oacc = MFMA32(at0, frag4(u0, u1, v0, v1), oacc);

      unsigned u2 = pk_bf16(sa0[8], sa0[9]),   u3 = pk_bf16(sa0[10], sa0[11]);
      unsigned v2 = pk_bf16(sa0[12], sa0[13]), v3 = pk_bf16(sa0[14], sa0[15]);
      plswap(u2, v2); plswap(u3, v3);
      s16x8 at1 = *(const s16x8*)(bt + lq*128 + (((2 + w) ^ (lq & 7)) << 4));
      oacc = MFMA32(at1, frag4(u2, u3, v2, v3), oacc);

      unsigned u4 = pk_bf16(sa1[0], sa1[1]),  u5 = pk_bf16(sa1[2], sa1[3]);
      unsigned v4 = pk_bf16(sa1[4], sa1[5]),  v5 = pk_bf16(sa1[6], sa1[7]);
      plswap(u4, v4); plswap(u5, v5);
      s16x8 at2 = *(const s16x8*)(bt + lq*128 + (((4 + w) ^ (lq & 7)) << 4));
      oacc = MFMA32(at2, frag4(u4, u5, v4, v5), oacc);

      unsigned u6 = pk_bf16(sa1[8], sa1[9]),   u7 = pk_bf16(sa1[10], sa1[11]);
      unsigned v6 = pk_bf16(sa1[12], sa1[13]), v7 = pk_bf16(sa1[14], sa1[15]);
      plswap(u6, v6); plswap(u7, v7);
      s16x8 at3 = *(const s16x8*)(bt + lq*128 + (((6 + w) ^ (lq & 7)) << 4));
      oacc = MFMA32(at3, frag4(u6, u7, v6, v7), oacc);
    }

    // ---- write staged tile kt+1 ----
    if (hn) {
      const int r = t >> 2, s4 = t & 3;
      unsigned h0 = bf16_hi_bits(va.x) | (bf16_hi_bits(va.y) << 16);
      unsigned h1 = bf16_hi_bits(va.z) | (bf16_hi_bits(va.w) << 16);
      unsigned h2 = bf16_hi_bits(vb.x) | (bf16_hi_bits(vb.y) << 16);
      unsigned h3 = bf16_hi_bits(vb.z) | (bf16_hi_bits(vb.w) << 16);
      unsigned l0 = bf16_hi_bits(va.x - __uint_as_float(h0<<16)) | (bf16_hi_bits(va.y - __uint_as_float(h0 & 0xffff0000u)) << 16);
      unsigned l1 = bf16_hi_bits(va.z - __uint_as_float(h1<<16)) | (bf16_hi_bits(va.w - __uint_as_float(h1 & 0xffff0000u)) << 16);
      unsigned l2 = bf16_hi_bits(vb.x - __uint_as_float(h2<<16)) | (bf16_hi_bits(vb.y - __uint_as_float(h2 & 0xffff0000u)) << 16);
      unsigned l3 = bf16_hi_bits(vb.z - __uint_as_float(h3<<16)) | (bf16_hi_bits(vb.w - __uint_as_float(h3 & 0xffff0000u)) << 16);
      int nb2 = cur ^ 1;
      int off = nb2*4096 + r*64 + ((s4 ^ (r & 3)) << 4);
      *(u32x4v*)(smem + off)        = (u32x4v){h0,h1,h2,h3};
      *(u32x4v*)(smem + 8192 + off) = (u32x4v){l0,l1,l2,l3};
      const int ci = t & 31;
      unsigned t0 = pk_bf16(c0,c1), t1 = pk_bf16(c2,c3), t2 = pk_bf16(c4,c5), t3 = pk_bf16(c6,c7);
      int toff = 16384 + nb2*4096 + ci*128 + (((t>>5) ^ (ci & 7)) << 4);
      *(u32x4v*)(smem + toff) = (u32x4v){t0,t1,t2,t3};
    }
    __syncthreads();
    cur ^= 1;
  }

  // ---- epilogue: Z^T = WvT * O_norm, coalesced store via per-wave LDS ----
  float inv = 1.0f / (16.0f * l);
  #pragma unroll
  for (int r = 0; r < 16; ++r) oacc[r] *= inv;
  s16x8 of0, of1;
  {
    unsigned u0 = pk_bf16(oacc[0], oacc[1]),  u1 = pk_bf16(oacc[2], oacc[3]);
    unsigned v0 = pk_bf16(oacc[4], oacc[5]),  v1 = pk_bf16(oacc[6], oacc[7]);
    plswap(u0, v0); plswap(u1, v1);
    of0 = frag4(u0, u1, v0, v1);
    unsigned u2 = pk_bf16(oacc[8], oacc[9]),   u3 = pk_bf16(oacc[10], oacc[11]);
    unsigned v2 = pk_bf16(oacc[12], oacc[13]), v3 = pk_bf16(oacc[14], oacc[15]);
    plswap(u2, v2); plswap(u3, v3);
    of1 = frag4(u2, u3, v2, v3);
  }
  const char* WvTb = (const char*)ws + 4224;
  float* zb = (float*)(smem + wid * 4224);
  const size_t orow = ((size_t)b * SEQ + q0 + wid*32);
  #pragma unroll 1
  for (int mt = 0; mt < 8; ++mt) {
    const char* wp = WvTb + (mt*32 + lq)*64 + 16*w;
    s16x8 a0 = *(const s16x8*)wp;
    s16x8 a1 = *(const s16x8*)(wp + 32);
    f32x16 z;
    #pragma unroll
    for (int r = 0; r < 16; ++r) z[r] = 0.f;
    z = MFMA32(a0, of0, z);
    z = MFMA32(a1, of1, z);
    #pragma unroll
    for (int r = 0; r < 16; ++r) {
      int hl = (r&3) + 8*(r>>2) + 4*w;
      zb[hl*33 + lq] = z[r];
    }
    asm volatile("s_waitcnt lgkmcnt(0)" ::: "memory");
    float bvv = bv[mt*32 + lq] * 0.0625f;
    #pragma unroll
    for (int jj = 0; jj < 16; ++jj) {
      int q = w*16 + jj;
      out[(orow + q)*HID + mt*32 + lq] = zb[lq*33 + q] + bvv;
    }
    asm volatile("s_waitcnt lgkmcnt(0)" ::: "memory");
  }
}

extern "C" void kernel_launch(void* const* d_in, const int* in_sizes, int n_in,
                              void* d_out, int out_size, void* d_ws, size_t ws_size,
                              hipStream_t stream) {
  (void)in_sizes; (void)n_in; (void)out_size; (void)ws_size;
  const float* x  = (const float*)d_in[0];
  const float* Wq = (const float*)d_in[1];
  const float* bq = (const float*)d_in[2];
  const float* Wk = (const float*)d_in[3];
  const float* Wv = (const float*)d_in[5];
  const float* bv = (const float*)d_in[6];
  float* out = (float*)d_out;
  float* ws  = (float*)d_ws;

  precompute_kernel<<<1, 256, 0, stream>>>(Wq, Wk, bq, Wv, ws);
  attn_kernel<<<dim3(SEQ/QT, NB), 256, 0, stream>>>(x, ws, bv, out);
}

// Round 6
// 64.963 us; speedup vs baseline: 6.8766x; 1.4612x over previous
//
#include <hip/hip_runtime.h>
#include <math.h>

#define NB   64
#define SEQ  1024
#define DIN  32
#define HID  256
#define QT   128
#define KT   64
#define NKT  (SEQ/KT)

typedef float        f32x16 __attribute__((ext_vector_type(16)));
typedef short        s16x8  __attribute__((ext_vector_type(8)));
typedef unsigned int u32x4v __attribute__((ext_vector_type(4)));
typedef unsigned int u32x2v __attribute__((ext_vector_type(2)));

#define MFMA32(A,B,C) __builtin_amdgcn_mfma_f32_32x32x16_bf16(A,B,C,0,0,0)

// per-group tile set: xk_h @+0 (4KB), xk_l @+4096, xkT @+8192 (12KB total)
#define SETB(g,p) (((g)*2+(p))*12288)
#define ATS_OFF   49152
#define SMEM_SZ   (ATS_OFF + 4224)

__device__ __forceinline__ unsigned pk_bf16(float lo, float hi) {
  unsigned r;
  asm("v_cvt_pk_bf16_f32 %0, %1, %2" : "=v"(r) : "v"(lo), "v"(hi));
  return r;
}
// new_dst = [dst.lo(lanes<32) | src.lo], new_src = [dst.hi | src.hi]
__device__ __forceinline__ void plswap(unsigned &vdst, unsigned &vsrc) {
  u32x2v r = __builtin_amdgcn_permlane32_swap(vdst, vsrc, false, false);
  vdst = r[0]; vsrc = r[1];
}
__device__ __forceinline__ float cross_max(float v) {
  u32x2v r = __builtin_amdgcn_permlane32_swap(__float_as_uint(v), __float_as_uint(v), false, false);
  return fmaxf(__uint_as_float(r[0]), __uint_as_float(r[1]));
}
__device__ __forceinline__ float cross_add(float v) {
  u32x2v r = __builtin_amdgcn_permlane32_swap(__float_as_uint(v), __float_as_uint(v), false, false);
  return __uint_as_float(r[0]) + __uint_as_float(r[1]);
}
__device__ __forceinline__ s16x8 frag4(unsigned a, unsigned b, unsigned c, unsigned d) {
  u32x4v t; t[0]=a; t[1]=b; t[2]=c; t[3]=d;
  return __builtin_bit_cast(s16x8, t);
}
__device__ __forceinline__ unsigned bf16_hi_bits(float f) {  // bf16 RNE bits in low16
  unsigned ux = __float_as_uint(f);
  return (ux + 0x7fffu + ((ux >> 16) & 1u)) >> 16;
}

// ws: f32 AT[32][32] (AT[i][j]=sum_h Wq[j,h]Wk[i,h]), f32 u[32],
// @byte 4224: u32 WvT[256][16] (pk-packed bf16 pairs of Wv^T rows).
// Parallel: 24 blocks x 256, one entry per thread.
__global__ void precompute_kernel(const float* __restrict__ Wq, const float* __restrict__ Wk,
                                  const float* __restrict__ bq, const float* __restrict__ Wv,
                                  float* __restrict__ ws) {
  const int gid = blockIdx.x * 256 + threadIdx.x;
  if (gid < 1024) {
    int i = gid >> 5, j = gid & 31;
    const float* a  = Wq + j * HID;
    const float* b2 = Wk + i * HID;
    float a0 = 0.f, a1 = 0.f, a2 = 0.f, a3 = 0.f;
    for (int h = 0; h < HID; h += 8) {
      float4 x1 = *(const float4*)(a + h);
      float4 y1 = *(const float4*)(b2 + h);
      float4 x2 = *(const float4*)(a + h + 4);
      float4 y2 = *(const float4*)(b2 + h + 4);
      a0 = fmaf(x1.x, y1.x, a0); a1 = fmaf(x1.y, y1.y, a1);
      a2 = fmaf(x1.z, y1.z, a2); a3 = fmaf(x1.w, y1.w, a3);
      a0 = fmaf(x2.x, y2.x, a0); a1 = fmaf(x2.y, y2.y, a1);
      a2 = fmaf(x2.z, y2.z, a2); a3 = fmaf(x2.w, y2.w, a3);
    }
    ws[gid] = (a0 + a1) + (a2 + a3);
  } else if (gid < 1056) {
    int i2 = gid - 1024;
    const float* b2 = Wk + i2 * HID;
    float acc = 0.f;
    for (int h = 0; h < HID; ++h) acc = fmaf(b2[h], bq[h], acc);
    ws[1024 + i2] = acc;
  } else if (gid < 1056 + HID * 16) {
    int e = gid - 1056;
    int h = e >> 4, d = e & 15;
    ((unsigned*)((char*)ws + 4224))[e] = pk_bf16(Wv[(2*d) * HID + h], Wv[(2*d+1) * HID + h]);
  }
}

// 512 threads = 8 waves: grp 0 (waves 0-3) handles even k-tiles, grp 1 odd.
// Flash-merge of (m,l,O) partials in LDS at the end; epilogue split by grp.
__global__ __launch_bounds__(512, 4) void attn_kernel(
    const float* __restrict__ x, const float* __restrict__ ws,
    const float* __restrict__ bv, float* __restrict__ out) {
  __shared__ __align__(16) char smem[SMEM_SZ];
  const int b    = blockIdx.y;
  const int q0   = blockIdx.x * QT;
  const int t    = threadIdx.x;
  const int grp  = t >> 8;        // k-split group
  const int ts   = t & 255;       // id within group (stager id)
  const int wid  = t >> 6;        // wave 0..7
  const int wq   = wid & 3;       // q-subtile owner within group
  const int lane = t & 63;
  const int w    = lane >> 5;
  const int lq   = lane & 31;
  const float* xb = x + (size_t)b * SEQ * DIN;

  float* ATs = (float*)(smem + ATS_OFF);
  for (int e = t; e < 1056; e += 512) ATs[e] = ws[e];

  // ---- prologue: grp g stages tile g into set(g,0) ----
  {
    const int sb = SETB(grp, 0);
    const int r = ts >> 2, s4 = ts & 3;
    const float* src = xb + (size_t)(grp * KT + r) * DIN + s4 * 8;
    float4 va = *(const float4*)src;
    float4 vb = *(const float4*)(src + 4);
    unsigned h0 = bf16_hi_bits(va.x) | (bf16_hi_bits(va.y) << 16);
    unsigned h1 = bf16_hi_bits(va.z) | (bf16_hi_bits(va.w) << 16);
    unsigned h2 = bf16_hi_bits(vb.x) | (bf16_hi_bits(vb.y) << 16);
    unsigned h3 = bf16_hi_bits(vb.z) | (bf16_hi_bits(vb.w) << 16);
    unsigned l0 = bf16_hi_bits(va.x - __uint_as_float(h0<<16)) | (bf16_hi_bits(va.y - __uint_as_float(h0 & 0xffff0000u)) << 16);
    unsigned l1 = bf16_hi_bits(va.z - __uint_as_float(h1<<16)) | (bf16_hi_bits(va.w - __uint_as_float(h1 & 0xffff0000u)) << 16);
    unsigned l2 = bf16_hi_bits(vb.x - __uint_as_float(h2<<16)) | (bf16_hi_bits(vb.y - __uint_as_float(h2 & 0xffff0000u)) << 16);
    unsigned l3 = bf16_hi_bits(vb.z - __uint_as_float(h3<<16)) | (bf16_hi_bits(vb.w - __uint_as_float(h3 & 0xffff0000u)) << 16);
    int off = r*64 + ((s4 ^ (r & 3)) << 4);
    *(u32x4v*)(smem + sb + off)        = (u32x4v){h0,h1,h2,h3};
    *(u32x4v*)(smem + sb + 4096 + off) = (u32x4v){l0,l1,l2,l3};
    const int ci = ts & 31, cr = (ts >> 5) * 8;
    const float* cs = xb + (size_t)(grp * KT + cr) * DIN + ci;
    float c0=cs[0], c1=cs[DIN], c2=cs[2*DIN], c3=cs[3*DIN];
    float c4=cs[4*DIN], c5=cs[5*DIN], c6=cs[6*DIN], c7=cs[7*DIN];
    unsigned t0 = pk_bf16(c0,c1), t1 = pk_bf16(c2,c3), t2 = pk_bf16(c4,c5), t3 = pk_bf16(c6,c7);
    int toff = sb + 8192 + ci*128 + (((ts>>5) ^ (ci & 7)) << 4);
    *(u32x4v*)(smem + toff) = (u32x4v){t0,t1,t2,t3};
  }
  __syncthreads();

  // ---- G' = xq*M + u, packed into B-fragments (hi/lo) ----
  float g[16];
  {
    float xq[32];
    const float* xrow = xb + (size_t)(q0 + wq*32 + lq) * DIN;
    #pragma unroll
    for (int c = 0; c < 8; ++c) {
      float4 v = *(const float4*)(xrow + c*4);
      xq[c*4+0]=v.x; xq[c*4+1]=v.y; xq[c*4+2]=v.z; xq[c*4+3]=v.w;
    }
    #pragma unroll
    for (int ii = 0; ii < 16; ++ii) {
      const int i = 8*w + 16*(ii>>3) + (ii&7);
      const float* ar = ATs + i*32;
      float acc = ATs[1024 + i];
      #pragma unroll
      for (int j = 0; j < 8; ++j) {
        float4 av = *(const float4*)(ar + j*4);
        acc = fmaf(xq[j*4+0], av.x, acc);
        acc = fmaf(xq[j*4+1], av.y, acc);
        acc = fmaf(xq[j*4+2], av.z, acc);
        acc = fmaf(xq[j*4+3], av.w, acc);
      }
      g[ii] = acc;
    }
  }
  s16x8 G0h, G0l, G1h, G1l;
  {
    unsigned gh[2][4], gl[2][4];
    #pragma unroll
    for (int Ks = 0; Ks < 2; ++Ks)
      #pragma unroll
      for (int d = 0; d < 4; ++d) {
        float ga = g[Ks*8 + 2*d], gb = g[Ks*8 + 2*d + 1];
        unsigned hp = bf16_hi_bits(ga) | (bf16_hi_bits(gb) << 16);
        unsigned lp = bf16_hi_bits(ga - __uint_as_float(hp<<16)) |
                      (bf16_hi_bits(gb - __uint_as_float(hp & 0xffff0000u)) << 16);
        gh[Ks][d] = hp; gl[Ks][d] = lp;
      }
    G0h = frag4(gh[0][0],gh[0][1],gh[0][2],gh[0][3]);
    G0l = frag4(gl[0][0],gl[0][1],gl[0][2],gl[0][3]);
    G1h = frag4(gh[1][0],gh[1][1],gh[1][2],gh[1][3]);
    G1l = frag4(gl[1][0],gl[1][1],gl[1][2],gl[1][3]);
  }

  f32x16 oacc;
  #pragma unroll
  for (int r = 0; r < 16; ++r) oacc[r] = 0.f;
  float m = -INFINITY, l = 0.f;

  for (int j = 0; j < NKT/2; ++j) {
    const bool hn = (j + 1 < NKT/2);
    float4 va, vb;
    float c0=0,c1=0,c2=0,c3=0,c4=0,c5=0,c6=0,c7=0;
    if (hn) {
      const int ktn = 2*(j+1) + grp;
      const int r = ts >> 2, s4 = ts & 3;
      const float* src = xb + (size_t)(ktn*KT + r) * DIN + s4*8;
      va = *(const float4*)src;
      vb = *(const float4*)(src + 4);
      const int ci = ts & 31, cr = (ts >> 5) * 8;
      const float* cs = xb + (size_t)(ktn*KT + cr) * DIN + ci;
      c0=cs[0]; c1=cs[DIN]; c2=cs[2*DIN]; c3=cs[3*DIN];
      c4=cs[4*DIN]; c5=cs[5*DIN]; c6=cs[6*DIN]; c7=cs[7*DIN];
    }

    // ---- GEMM1: S^T[64k x 32q] ----
    const int sb = SETB(grp, j & 1);
    const char* bh = smem + sb;
    const char* bl = smem + sb + 4096;
    const int co0 = ((w    ) ^ (lq & 3)) << 4;
    const int co1 = ((w + 2) ^ (lq & 3)) << 4;
    s16x8 ah00 = *(const s16x8*)(bh + lq*64 + co0);
    s16x8 ah01 = *(const s16x8*)(bh + lq*64 + co1);
    s16x8 al00 = *(const s16x8*)(bl + lq*64 + co0);
    s16x8 al01 = *(const s16x8*)(bl + lq*64 + co1);
    s16x8 ah10 = *(const s16x8*)(bh + (32+lq)*64 + co0);
    s16x8 ah11 = *(const s16x8*)(bh + (32+lq)*64 + co1);
    s16x8 al10 = *(const s16x8*)(bl + (32+lq)*64 + co0);
    s16x8 al11 = *(const s16x8*)(bl + (32+lq)*64 + co1);
    f32x16 sa0, sa1;
    #pragma unroll
    for (int r = 0; r < 16; ++r) { sa0[r] = 0.f; sa1[r] = 0.f; }
    sa0 = MFMA32(ah00, G0h, sa0); sa0 = MFMA32(ah00, G0l, sa0); sa0 = MFMA32(al00, G0h, sa0);
    sa0 = MFMA32(ah01, G1h, sa0); sa0 = MFMA32(ah01, G1l, sa0); sa0 = MFMA32(al01, G1h, sa0);
    sa1 = MFMA32(ah10, G0h, sa1); sa1 = MFMA32(ah10, G0l, sa1); sa1 = MFMA32(al10, G0h, sa1);
    sa1 = MFMA32(ah11, G1h, sa1); sa1 = MFMA32(ah11, G1l, sa1); sa1 = MFMA32(al11, G1h, sa1);

    // ---- online softmax (per q = lq; partner lane holds other keys) ----
    float tm = sa0[0];
    #pragma unroll
    for (int r = 1; r < 16; ++r) tm = fmaxf(tm, sa0[r]);
    #pragma unroll
    for (int r = 0; r < 16; ++r) tm = fmaxf(tm, sa1[r]);
    tm = cross_max(tm);
    float mn = fmaxf(m, tm);
    float alpha = __expf(m - mn);
    m = mn;
    float ps = 0.f;
    #pragma unroll
    for (int r = 0; r < 16; ++r) { float p = __expf(sa0[r] - mn); sa0[r] = p; ps += p; }
    #pragma unroll
    for (int r = 0; r < 16; ++r) { float p = __expf(sa1[r] - mn); sa1[r] = p; ps += p; }
    ps = cross_add(ps);
    l = l * alpha + ps;
    #pragma unroll
    for (int r = 0; r < 16; ++r) oacc[r] *= alpha;

    // ---- GEMM2: O^T += xkT * P (P repacked in-register; dst=low-pair) ----
    const char* bt = smem + sb + 8192;
    {
      unsigned u0 = pk_bf16(sa0[0], sa0[1]),  u1 = pk_bf16(sa0[2], sa0[3]);
      unsigned v0 = pk_bf16(sa0[4], sa0[5]),  v1 = pk_bf16(sa0[6], sa0[7]);
      plswap(u0, v0); plswap(u1, v1);
      s16x8 at0 = *(const s16x8*)(bt + lq*128 + (((0 + w) ^ (lq & 7)) << 4));
      oacc = MFMA32(at0, frag4(u0, u1, v0, v1), oacc);

      unsigned u2 = pk_bf16(sa0[8], sa0[9]),   u3 = pk_bf16(sa0[10], sa0[11]);
      unsigned v2 = pk_bf16(sa0[12], sa0[13]), v3 = pk_bf16(sa0[14], sa0[15]);
      plswap(u2, v2); plswap(u3, v3);
      s16x8 at1 = *(const s16x8*)(bt + lq*128 + (((2 + w) ^ (lq & 7)) << 4));
      oacc = MFMA32(at1, frag4(u2, u3, v2, v3), oacc);

      unsigned u4 = pk_bf16(sa1[0], sa1[1]),  u5 = pk_bf16(sa1[2], sa1[3]);
      unsigned v4 = pk_bf16(sa1[4], sa1[5]),  v5 = pk_bf16(sa1[6], sa1[7]);
      plswap(u4, v4); plswap(u5, v5);
      s16x8 at2 = *(const s16x8*)(bt + lq*128 + (((4 + w) ^ (lq & 7)) << 4));
      oacc = MFMA32(at2, frag4(u4, u5, v4, v5), oacc);

      unsigned u6 = pk_bf16(sa1[8], sa1[9]),   u7 = pk_bf16(sa1[10], sa1[11]);
      unsigned v6 = pk_bf16(sa1[12], sa1[13]), v7 = pk_bf16(sa1[14], sa1[15]);
      plswap(u6, v6); plswap(u7, v7);
      s16x8 at3 = *(const s16x8*)(bt + lq*128 + (((6 + w) ^ (lq & 7)) << 4));
      oacc = MFMA32(at3, frag4(u6, u7, v6, v7), oacc);
    }

    // ---- write staged next tile into set(grp, (j+1)&1) ----
    if (hn) {
      const int nsb = SETB(grp, (j+1) & 1);
      const int r = ts >> 2, s4 = ts & 3;
      unsigned h0 = bf16_hi_bits(va.x) | (bf16_hi_bits(va.y) << 16);
      unsigned h1 = bf16_hi_bits(va.z) | (bf16_hi_bits(va.w) << 16);
      unsigned h2 = bf16_hi_bits(vb.x) | (bf16_hi_bits(vb.y) << 16);
      unsigned h3 = bf16_hi_bits(vb.z) | (bf16_hi_bits(vb.w) << 16);
      unsigned l0 = bf16_hi_bits(va.x - __uint_as_float(h0<<16)) | (bf16_hi_bits(va.y - __uint_as_float(h0 & 0xffff0000u)) << 16);
      unsigned l1 = bf16_hi_bits(va.z - __uint_as_float(h1<<16)) | (bf16_hi_bits(va.w - __uint_as_float(h1 & 0xffff0000u)) << 16);
      unsigned l2 = bf16_hi_bits(vb.x - __uint_as_float(h2<<16)) | (bf16_hi_bits(vb.y - __uint_as_float(h2 & 0xffff0000u)) << 16);
      unsigned l3 = bf16_hi_bits(vb.z - __uint_as_float(h3<<16)) | (bf16_hi_bits(vb.w - __uint_as_float(h3 & 0xffff0000u)) << 16);
      int off = r*64 + ((s4 ^ (r & 3)) << 4);
      *(u32x4v*)(smem + nsb + off)        = (u32x4v){h0,h1,h2,h3};
      *(u32x4v*)(smem + nsb + 4096 + off) = (u32x4v){l0,l1,l2,l3};
      const int ci = ts & 31;
      unsigned t0 = pk_bf16(c0,c1), t1 = pk_bf16(c2,c3), t2 = pk_bf16(c4,c5), t3 = pk_bf16(c6,c7);
      int toff = nsb + 8192 + ci*128 + (((ts>>5) ^ (ci & 7)) << 4);
      *(u32x4v*)(smem + toff) = (u32x4v){t0,t1,t2,t3};
    }
    __syncthreads();
  }

  // ---- flash-merge partials across the two k-groups (symmetric) ----
  {
    float* ms = (float*)(smem + grp*20480 + (((wq<<6) | lane) * 80));
    *(float4*)(ms + 0)  = (float4){oacc[0],  oacc[1],  oacc[2],  oacc[3]};
    *(float4*)(ms + 4)  = (float4){oacc[4],  oacc[5],  oacc[6],  oacc[7]};
    *(float4*)(ms + 8)  = (float4){oacc[8],  oacc[9],  oacc[10], oacc[11]};
    *(float4*)(ms + 12) = (float4){oacc[12], oacc[13], oacc[14], oacc[15]};
    ms[16] = m; ms[17] = l;
    __syncthreads();
    const float* pp = (const float*)(smem + (1-grp)*20480 + (((wq<<6) | lane) * 80));
    float4 p0 = *(const float4*)(pp + 0);
    float4 p1 = *(const float4*)(pp + 4);
    float4 p2 = *(const float4*)(pp + 8);
    float4 p3 = *(const float4*)(pp + 12);
    float pm = pp[16], pl = pp[17];
    float mf = fmaxf(m, pm);
    float as = __expf(m - mf), ap = __expf(pm - mf);
    l = l * as + pl * ap;
    float po[16] = {p0.x,p0.y,p0.z,p0.w, p1.x,p1.y,p1.z,p1.w,
                    p2.x,p2.y,p2.z,p2.w, p3.x,p3.y,p3.z,p3.w};
    #pragma unroll
    for (int r = 0; r < 16; ++r) oacc[r] = oacc[r] * as + po[r] * ap;
    __syncthreads();   // before zb reuse of this region
  }

  // ---- epilogue: Z^T = WvT * O_norm; grp handles its half of HID ----
  float inv = 1.0f / (16.0f * l);
  #pragma unroll
  for (int r = 0; r < 16; ++r) oacc[r] *= inv;
  s16x8 of0, of1;
  {
    unsigned u0 = pk_bf16(oacc[0], oacc[1]),  u1 = pk_bf16(oacc[2], oacc[3]);
    unsigned v0 = pk_bf16(oacc[4], oacc[5]),  v1 = pk_bf16(oacc[6], oacc[7]);
    plswap(u0, v0); plswap(u1, v1);
    of0 = frag4(u0, u1, v0, v1);
    unsigned u2 = pk_bf16(oacc[8], oacc[9]),   u3 = pk_bf16(oacc[10], oacc[11]);
    unsigned v2 = pk_bf16(oacc[12], oacc[13]), v3 = pk_bf16(oacc[14], oacc[15]);
    plswap(u2, v2); plswap(u3, v3);
    of1 = frag4(u2, u3, v2, v3);
  }
  const char* WvTb = (const char*)ws + 4224;
  float* zb = (float*)(smem + wid * 4224);
  const size_t orow = ((size_t)b * SEQ + q0 + wq*32);
  #pragma unroll 1
  for (int mi = 0; mi < 4; ++mi) {
    const int mt = grp*4 + mi;
    const char* wp = WvTb + (mt*32 + lq)*64 + 16*w;
    s16x8 a0 = *(const s16x8*)wp;
    s16x8 a1 = *(const s16x8*)(wp + 32);
    f32x16 z;
    #pragma unroll
    for (int r = 0; r < 16; ++r) z[r] = 0.f;
    z = MFMA32(a0, of0, z);
    z = MFMA32(a1, of1, z);
    #pragma unroll
    for (int r = 0; r < 16; ++r) {
      int hl = (r&3) + 8*(r>>2) + 4*w;
      zb[hl*33 + lq] = z[r];
    }
    asm volatile("s_waitcnt lgkmcnt(0)" ::: "memory");
    float bvv = bv[mt*32 + lq] * 0.0625f;
    #pragma unroll
    for (int jj = 0; jj < 16; ++jj) {
      int q = w*16 + jj;
      out[(orow + q)*HID + mt*32 + lq] = zb[lq*33 + q] + bvv;
    }
    asm volatile("s_waitcnt lgkmcnt(0)" ::: "memory");
  }
}

extern "C" void kernel_launch(void* const* d_in, const int* in_sizes, int n_in,
                              void* d_out, int out_size, void* d_ws, size_t ws_size,
                              hipStream_t stream) {
  (void)in_sizes; (void)n_in; (void)out_size; (void)ws_size;
  const float* x  = (const float*)d_in[0];
  const float* Wq = (const float*)d_in[1];
  const float* bq = (const float*)d_in[2];
  const float* Wk = (const float*)d_in[3];
  const float* Wv = (const float*)d_in[5];
  const float* bv = (const float*)d_in[6];
  float* out = (float*)d_out;
  float* ws  = (float*)d_ws;

  precompute_kernel<<<24, 256, 0, stream>>>(Wq, Wk, bq, Wv, ws);
  attn_kernel<<<dim3(SEQ/QT, NB), 512, 0, stream>>>(x, ws, bv, out);
}